// Round 4
// baseline (128.243 us; speedup 1.0000x reference)
//
#include <hip/hip_runtime.h>

#define SRC_LEN 256
#define TRG_LEN 256
#define BATCH   32
#define HID     512
#define ATT     128
#define CSCALE  2.885390081777927f   // 2*log2(e): exp2(CSCALE*x) == exp(2x)

typedef float  f32x4  __attribute__((ext_vector_type(4)));
typedef short  bf16x8 __attribute__((ext_vector_type(8)));

// manual RNE fp32->bf16 (inputs are finite normals; NaN path not needed)
__device__ inline unsigned short bfr(float x) {
    unsigned u = __builtin_bit_cast(unsigned, x);
    return (unsigned short)((u + 0x7fffu + ((u >> 16) & 1u)) >> 16);
}
__device__ inline unsigned pk2(float a, float b) {
    return (unsigned)bfr(a) | ((unsigned)bfr(b) << 16);
}

// ---------------------------------------------------------------------------
// MFMA projection v5 (R0 measured-good version, ~25-31 us): 64 rows x 128 a
// tile, K=512 in 8 chunks, 256 blocks x 512 threads, validated LDS swizzle +
// coalesced staging. Verbatim.
// ---------------------------------------------------------------------------
__global__ __launch_bounds__(512) void proj_mfma(
    const float* __restrict__ dec_out, const float* __restrict__ enc_outs,
    const float* __restrict__ W_s, const float* __restrict__ W_t,
    const float* __restrict__ b_t,
    float* __restrict__ encE, float* __restrict__ decD)
{
    __shared__ __align__(16) char smem[49152];
    char* aLb = smem;            // [2][64 rows][128 B] = 16 KB
    char* bLb = smem + 16384;    // [2][128 rows][128 B] = 32 KB

    const int tid   = threadIdx.x;
    const int blk   = blockIdx.x;
    const bool isDec = blk >= 128;
    const int bb    = blk & 31;
    const int r0    = ((isDec ? blk - 128 : blk) >> 5) * 64;  // s0 or t0
    const float* __restrict__ in = isDec ? dec_out : enc_outs;
    const float* __restrict__ W  = isDec ? W_t : W_s;

    const int lane   = tid & 63;
    const int w      = tid >> 6;        // 0..7
    const int woff_m = (w & 3) * 16;
    const int woff_n = (w >> 2) * 64;
    const int q      = lane >> 4;
    const int l15    = lane & 15;
    const int l7     = lane & 7;

    const int srow = tid >> 4;
    const int skc  = tid & 15;
    const int sg   = skc >> 1, shalf = skc & 1;
    const float* aGp = in + ((size_t)(r0 + srow) * BATCH + bb) * HID + skc * 4;
    const float* wGp = W + (size_t)srow * HID + skc * 4;

    float4 aR[2];   // A rows srow, srow+32
    float4 wR[4];   // W rows srow + it*32

    f32x4 acc[4];
    #pragma unroll
    for (int ni = 0; ni < 4; ++ni) acc[ni] = (f32x4)0.0f;

    #define LOADG(c)                                                          \
        {                                                                     \
            _Pragma("unroll")                                                 \
            for (int it = 0; it < 2; ++it)                                    \
                aR[it] = *(const float4*)(aGp + (size_t)it * 32 * BATCH * HID \
                                          + (c) * 64);                        \
            _Pragma("unroll")                                                 \
            for (int it = 0; it < 4; ++it)                                    \
                wR[it] = *(const float4*)(wGp + (size_t)it * 32 * HID         \
                                          + (c) * 64);                        \
        }

    #define STORES(buf)                                                      \
        {                                                                    \
            char* ab = aLb + (buf) * 8192;                                   \
            _Pragma("unroll")                                                \
            for (int it = 0; it < 2; ++it) {                                 \
                const int i = srow + it * 32;                                \
                uint2 u;                                                     \
                u.x = pk2(aR[it].x, aR[it].y);                               \
                u.y = pk2(aR[it].z, aR[it].w);                               \
                *(uint2*)(ab + i * 128 + ((sg ^ (i & 7)) << 4)               \
                          + shalf * 8) = u;                                  \
            }                                                                \
            char* bp = bLb + (buf) * 16384;                                  \
            _Pragma("unroll")                                                \
            for (int it = 0; it < 4; ++it) {                                 \
                const int rw = srow + it * 32;                               \
                uint2 u;                                                     \
                u.x = pk2(wR[it].x, wR[it].y);                               \
                u.y = pk2(wR[it].z, wR[it].w);                               \
                *(uint2*)(bp + rw * 128 + ((sg ^ (rw & 7)) << 4)             \
                          + shalf * 8) = u;                                  \
            }                                                                \
        }

    LOADG(0);
    STORES(0);
    __syncthreads();

    for (int c = 0; c < 8; ++c) {
        if (c < 7) LOADG(c + 1);
        const char* ab = aLb + (c & 1) * 8192;
        const char* bp = bLb + (c & 1) * 16384;
        #pragma unroll
        for (int s = 0; s < 2; ++s) {
            const int sw = ((s * 4 + q) ^ l7) * 16;
            bf16x8 af = *(const bf16x8*)(ab + (woff_m + l15) * 128 + sw);
            bf16x8 bfv[4];
            #pragma unroll
            for (int ni = 0; ni < 4; ++ni)
                bfv[ni] = *(const bf16x8*)(bp + (woff_n + ni * 16 + l15) * 128 + sw);
            #pragma unroll
            for (int ni = 0; ni < 4; ++ni)
                acc[ni] = __builtin_amdgcn_mfma_f32_16x16x32_bf16(
                    af, bfv[ni], acc[ni], 0, 0, 0);
        }
        if (c < 7) STORES((c + 1) & 1);
        __syncthreads();
    }

    if (!isDec) {
        // E' = exp(-2*enc_att) -> LDS transpose (stride 132, float4-aligned)
        // -> [b][a>>2][s][4] store: one coalesced float4 per lane for score.
        float* T = (float*)smem;
        #pragma unroll
        for (int ni = 0; ni < 4; ++ni)
            #pragma unroll
            for (int r = 0; r < 4; ++r) {
                const int ml = woff_m + q * 4 + r;
                const int nl = woff_n + ni * 16 + l15;
                T[ml * 132 + nl] = __builtin_amdgcn_exp2f(-CSCALE * acc[ni][r]);
            }
        __syncthreads();
        {
            const int m  = tid & 63;     // s-local
            const int g0 = tid >> 6;     // 0..7
            #pragma unroll
            for (int p = 0; p < 4; ++p) {
                const int gq = g0 + p * 8;          // a-quad 0..31
                float4 v = *(const float4*)(T + m * 132 + gq * 4);
                *(float4*)(encE + (((size_t)bb * 32 + gq) * SRC_LEN + r0 + m) * 4) = v;
            }
        }
    } else {
        // D = exp(+2*(dec_att + b_t)), natural [t][b][a] store
        float bt[4];
        #pragma unroll
        for (int ni = 0; ni < 4; ++ni) bt[ni] = b_t[woff_n + ni * 16 + l15];
        #pragma unroll
        for (int ni = 0; ni < 4; ++ni)
            #pragma unroll
            for (int r = 0; r < 4; ++r) {
                const int ml = woff_m + q * 4 + r;
                const int nl = woff_n + ni * 16 + l15;
                decD[((size_t)(r0 + ml) * BATCH + bb) * ATT + nl] =
                    __builtin_amdgcn_exp2f(CSCALE * (acc[ni][r] + bt[ni]));
            }
    }
    #undef LOADG
    #undef STORES
}

// ---------------------------------------------------------------------------
// Score v9b: s-TILING (4 t x 4 s = 16 outputs/thread) — R3 structure with the
// staging bug fixed: dS is 16 rows x 128 floats = 512 float4s; R3 wrote only
// 256 (upper half of every row uninitialized -> absmax 6.7e5). Now staged in
// TWO fully-coalesced passes (tr = tid>>5 + p*8, a4 = (tid&31)*4).
// Rationale unchanged: per-output LDS slots / loop overhead / E-load traffic
// all /4; per-output VALU (the ~14 us floor) unchanged; 16 independent
// chains per g give ILP to cover 2-wave/SIMD occupancy.
// ---------------------------------------------------------------------------
__global__ __launch_bounds__(256) void score_kernel(
    const float* __restrict__ encE, const float* __restrict__ decD,
    const float* __restrict__ v_a, float* __restrict__ out)
{
    __shared__ __align__(16) float dS[16][ATT];
    __shared__ float vS[ATT];
    __shared__ float sumvS;

    const int tid = threadIdx.x;
    const int t0  = blockIdx.x * 16;
    const int b   = blockIdx.y;

    // stage decD rows t0..t0+15: 2 passes x (8 rows x 32 float4), coalesced
    {
        const int tr0 = tid >> 5;          // 0..7
        const int a4  = (tid & 31) * 4;    // 0..124
        #pragma unroll
        for (int p = 0; p < 2; ++p) {
            const int tr = tr0 + p * 8;
            *(float4*)(&dS[tr][a4]) =
                *(const float4*)(decD + ((size_t)(t0 + tr) * BATCH + b) * ATT + a4);
        }
    }
    if (tid < 32) *(float4*)(vS + tid * 4) = *(const float4*)(v_a + tid * 4);
    __syncthreads();
    if (tid < 64) {
        float x = vS[tid] + vS[tid + 64];
        #pragma unroll
        for (int o = 32; o > 0; o >>= 1) x += __shfl_down(x, o);
        if (tid == 0) sumvS = x;
    }
    __syncthreads();

    const int w  = tid >> 6;        // wave -> t-quad (t = t0 + w*4 + i)
    const int l  = tid & 63;
    const int s0 = l * 4;           // this thread's 4 s-values

    f32x4 acc[4];                   // acc[i][si]
    #pragma unroll
    for (int i = 0; i < 4; ++i) acc[i] = (f32x4)0.0f;

    // encE flat float index: b*32768 + g*1024 + s*4 + j
    const float* __restrict__ ep = encE + (size_t)b * 32 * SRC_LEN * 4 + s0 * 4;

    #pragma unroll 4
    for (int g = 0; g < 32; ++g) {
        const float* epg = ep + (size_t)g * SRC_LEN * 4;
        float4 E[4];
        #pragma unroll
        for (int si = 0; si < 4; ++si)
            E[si] = *(const float4*)(epg + si * 4);          // 64B contiguous
        const float4 vv = *(const float4*)(vS + g * 4);      // broadcast
        float4 n[4];
        #pragma unroll
        for (int si = 0; si < 4; ++si) {
            n[si].x = vv.x * E[si].x; n[si].y = vv.y * E[si].y;
            n[si].z = vv.z * E[si].z; n[si].w = vv.w * E[si].w;
        }
        #pragma unroll
        for (int i = 0; i < 4; ++i) {
            const float4 d = *(const float4*)(&dS[w * 4 + i][g * 4]);  // broadcast
            #pragma unroll
            for (int si = 0; si < 4; ++si) {
                const float x0 = E[si].x + d.x, x1 = E[si].y + d.y;
                const float x2 = E[si].z + d.z, x3 = E[si].w + d.w;
                const float a01 = x0 * x1, a23 = x2 * x3;
                const float den = a01 * a23;
                const float m01 = fmaf(n[si].x, x1, n[si].y * x0);
                const float m23 = fmaf(n[si].z, x3, n[si].w * x2);
                const float num = fmaf(m01, a23, m23 * a01);
                acc[i][si] = fmaf(num, __builtin_amdgcn_rcpf(den), acc[i][si]);
            }
        }
    }

    const float sv = sumvS;
    #pragma unroll
    for (int i = 0; i < 4; ++i) {
        float4 o;
        o.x = sv - 2.0f * acc[i][0];
        o.y = sv - 2.0f * acc[i][1];
        o.z = sv - 2.0f * acc[i][2];
        o.w = sv - 2.0f * acc[i][3];
        *(float4*)(out + ((size_t)(t0 + w * 4 + i) * BATCH + b) * SRC_LEN + s0) = o;
    }
}

extern "C" void kernel_launch(void* const* d_in, const int* in_sizes, int n_in,
                              void* d_out, int out_size, void* d_ws, size_t ws_size,
                              hipStream_t stream) {
    const float* dec_out  = (const float*)d_in[0];
    const float* enc_outs = (const float*)d_in[1];
    const float* W_s      = (const float*)d_in[2];
    const float* W_t      = (const float*)d_in[3];
    const float* b_t      = (const float*)d_in[4];
    const float* v_a      = (const float*)d_in[5];
    float* out = (float*)d_out;

    float* encE = (float*)d_ws;                              // B*32*S*4 = 4 MB : exp(-2*enc_att), [b][a>>2][s][4]
    float* decD = encE + (size_t)BATCH * ATT * SRC_LEN;      // T*B*A    = 4 MB : exp(+2*dec_att), [t][b][a]

    proj_mfma<<<256, 512, 0, stream>>>(dec_out, enc_outs, W_s, W_t, b_t, encE, decD);

    score_kernel<<<dim3(16, BATCH), 256, 0, stream>>>(encE, decD, v_a, out);
}

// Round 5
// 127.017 us; speedup vs baseline: 1.0097x; 1.0097x over previous
//
#include <hip/hip_runtime.h>

#define SRC_LEN 256
#define TRG_LEN 256
#define BATCH   32
#define HID     512
#define ATT     128
#define CSCALE  2.885390081777927f   // 2*log2(e): exp2(CSCALE*x) == exp(2x)

typedef float  f32x4  __attribute__((ext_vector_type(4)));
typedef short  bf16x8 __attribute__((ext_vector_type(8)));

// manual RNE fp32->bf16 (inputs are finite normals; NaN path not needed)
__device__ inline unsigned short bfr(float x) {
    unsigned u = __builtin_bit_cast(unsigned, x);
    return (unsigned short)((u + 0x7fffu + ((u >> 16) & 1u)) >> 16);
}
__device__ inline unsigned pk2(float a, float b) {
    return (unsigned)bfr(a) | ((unsigned)bfr(b) << 16);
}

// ---------------------------------------------------------------------------
// MFMA projection v5 (R0 measured-good version, ~25-31 us): 64 rows x 128 a
// tile, K=512 in 8 chunks, 256 blocks x 512 threads, validated LDS swizzle +
// coalesced staging. Verbatim — do not touch until score is settled.
// ---------------------------------------------------------------------------
__global__ __launch_bounds__(512) void proj_mfma(
    const float* __restrict__ dec_out, const float* __restrict__ enc_outs,
    const float* __restrict__ W_s, const float* __restrict__ W_t,
    const float* __restrict__ b_t,
    float* __restrict__ encE, float* __restrict__ decD)
{
    __shared__ __align__(16) char smem[49152];
    char* aLb = smem;            // [2][64 rows][128 B] = 16 KB
    char* bLb = smem + 16384;    // [2][128 rows][128 B] = 32 KB

    const int tid   = threadIdx.x;
    const int blk   = blockIdx.x;
    const bool isDec = blk >= 128;
    const int bb    = blk & 31;
    const int r0    = ((isDec ? blk - 128 : blk) >> 5) * 64;  // s0 or t0
    const float* __restrict__ in = isDec ? dec_out : enc_outs;
    const float* __restrict__ W  = isDec ? W_t : W_s;

    const int lane   = tid & 63;
    const int w      = tid >> 6;        // 0..7
    const int woff_m = (w & 3) * 16;
    const int woff_n = (w >> 2) * 64;
    const int q      = lane >> 4;
    const int l15    = lane & 15;
    const int l7     = lane & 7;

    const int srow = tid >> 4;
    const int skc  = tid & 15;
    const int sg   = skc >> 1, shalf = skc & 1;
    const float* aGp = in + ((size_t)(r0 + srow) * BATCH + bb) * HID + skc * 4;
    const float* wGp = W + (size_t)srow * HID + skc * 4;

    float4 aR[2];   // A rows srow, srow+32
    float4 wR[4];   // W rows srow + it*32

    f32x4 acc[4];
    #pragma unroll
    for (int ni = 0; ni < 4; ++ni) acc[ni] = (f32x4)0.0f;

    #define LOADG(c)                                                          \
        {                                                                     \
            _Pragma("unroll")                                                 \
            for (int it = 0; it < 2; ++it)                                    \
                aR[it] = *(const float4*)(aGp + (size_t)it * 32 * BATCH * HID \
                                          + (c) * 64);                        \
            _Pragma("unroll")                                                 \
            for (int it = 0; it < 4; ++it)                                    \
                wR[it] = *(const float4*)(wGp + (size_t)it * 32 * HID         \
                                          + (c) * 64);                        \
        }

    #define STORES(buf)                                                      \
        {                                                                    \
            char* ab = aLb + (buf) * 8192;                                   \
            _Pragma("unroll")                                                \
            for (int it = 0; it < 2; ++it) {                                 \
                const int i = srow + it * 32;                                \
                uint2 u;                                                     \
                u.x = pk2(aR[it].x, aR[it].y);                               \
                u.y = pk2(aR[it].z, aR[it].w);                               \
                *(uint2*)(ab + i * 128 + ((sg ^ (i & 7)) << 4)               \
                          + shalf * 8) = u;                                  \
            }                                                                \
            char* bp = bLb + (buf) * 16384;                                  \
            _Pragma("unroll")                                                \
            for (int it = 0; it < 4; ++it) {                                 \
                const int rw = srow + it * 32;                               \
                uint2 u;                                                     \
                u.x = pk2(wR[it].x, wR[it].y);                               \
                u.y = pk2(wR[it].z, wR[it].w);                               \
                *(uint2*)(bp + rw * 128 + ((sg ^ (rw & 7)) << 4)             \
                          + shalf * 8) = u;                                  \
            }                                                                \
        }

    LOADG(0);
    STORES(0);
    __syncthreads();

    for (int c = 0; c < 8; ++c) {
        if (c < 7) LOADG(c + 1);
        const char* ab = aLb + (c & 1) * 8192;
        const char* bp = bLb + (c & 1) * 16384;
        #pragma unroll
        for (int s = 0; s < 2; ++s) {
            const int sw = ((s * 4 + q) ^ l7) * 16;
            bf16x8 af = *(const bf16x8*)(ab + (woff_m + l15) * 128 + sw);
            bf16x8 bfv[4];
            #pragma unroll
            for (int ni = 0; ni < 4; ++ni)
                bfv[ni] = *(const bf16x8*)(bp + (woff_n + ni * 16 + l15) * 128 + sw);
            #pragma unroll
            for (int ni = 0; ni < 4; ++ni)
                acc[ni] = __builtin_amdgcn_mfma_f32_16x16x32_bf16(
                    af, bfv[ni], acc[ni], 0, 0, 0);
        }
        if (c < 7) STORES((c + 1) & 1);
        __syncthreads();
    }

    if (!isDec) {
        // E' = exp(-2*enc_att) -> LDS transpose (stride 132, float4-aligned)
        // -> [b][a>>2][s][4] store: one coalesced float4 per lane for score.
        float* T = (float*)smem;
        #pragma unroll
        for (int ni = 0; ni < 4; ++ni)
            #pragma unroll
            for (int r = 0; r < 4; ++r) {
                const int ml = woff_m + q * 4 + r;
                const int nl = woff_n + ni * 16 + l15;
                T[ml * 132 + nl] = __builtin_amdgcn_exp2f(-CSCALE * acc[ni][r]);
            }
        __syncthreads();
        {
            const int m  = tid & 63;     // s-local
            const int g0 = tid >> 6;     // 0..7
            #pragma unroll
            for (int p = 0; p < 4; ++p) {
                const int gq = g0 + p * 8;          // a-quad 0..31
                float4 v = *(const float4*)(T + m * 132 + gq * 4);
                *(float4*)(encE + (((size_t)bb * 32 + gq) * SRC_LEN + r0 + m) * 4) = v;
            }
        }
    } else {
        // D = exp(+2*(dec_att + b_t)), natural [t][b][a] store
        float bt[4];
        #pragma unroll
        for (int ni = 0; ni < 4; ++ni) bt[ni] = b_t[woff_n + ni * 16 + l15];
        #pragma unroll
        for (int ni = 0; ni < 4; ++ni)
            #pragma unroll
            for (int r = 0; r < 4; ++r) {
                const int ml = woff_m + q * 4 + r;
                const int nl = woff_n + ni * 16 + l15;
                decD[((size_t)(r0 + ml) * BATCH + bb) * ATT + nl] =
                    __builtin_amdgcn_exp2f(CSCALE * (acc[ni][r] + bt[ni]));
            }
    }
    #undef LOADG
    #undef STORES
}

// ---------------------------------------------------------------------------
// Score v10: 4t x 2s = 8 outputs/thread — the occupancy/overhead midpoint.
// R4 counters: v9b (16 out/thread, 512 blocks) = 44.6 us, VALUBusy 49%,
// Occupancy 15.6% -> latency-bound at 2 waves/SIMD. v6 (4 out/thread,
// 2048 blocks) = ~36.5 us -> overhead-bound at 8 waves/SIMD. v10: 1024
// blocks = 4 blocks/CU = 4 waves/SIMD (50% occ), E bytes/output stays at
// the optimal 4B (t-share 4), d/v stay LDS broadcasts, 8 independent
// rational chains/thread for ILP. Occupancy is grid-limited, so VGPR up
// to 128 is free -> unroll 4 lets the compiler prefetch E across g.
// Block covers 16t x 128s; grid ((16 tq)*(2 sh), 32 b).
// ---------------------------------------------------------------------------
__global__ __launch_bounds__(256) void score_kernel(
    const float* __restrict__ encE, const float* __restrict__ decD,
    const float* __restrict__ v_a, float* __restrict__ out)
{
    __shared__ __align__(16) float dS[16][ATT];
    __shared__ float vS[ATT];
    __shared__ float sumvS;

    const int tid = threadIdx.x;
    const int tq  = blockIdx.x >> 1;
    const int sh  = blockIdx.x & 1;
    const int t0  = tq * 16;
    const int sbase = sh * 128;
    const int b   = blockIdx.y;

    // stage decD rows t0..t0+15: 2 passes x (8 rows x 32 float4), coalesced
    {
        const int tr0 = tid >> 5;          // 0..7
        const int a4  = (tid & 31) * 4;    // 0..124
        #pragma unroll
        for (int p = 0; p < 2; ++p) {
            const int tr = tr0 + p * 8;
            *(float4*)(&dS[tr][a4]) =
                *(const float4*)(decD + ((size_t)(t0 + tr) * BATCH + b) * ATT + a4);
        }
    }
    if (tid < 32) *(float4*)(vS + tid * 4) = *(const float4*)(v_a + tid * 4);
    __syncthreads();
    if (tid < 64) {
        float x = vS[tid] + vS[tid + 64];
        #pragma unroll
        for (int o = 32; o > 0; o >>= 1) x += __shfl_down(x, o);
        if (tid == 0) sumvS = x;
    }
    __syncthreads();

    const int w  = tid >> 6;        // wave -> t-quad (t = t0 + w*4 + i)
    const int l  = tid & 63;
    const int s0 = sbase + l * 2;   // this thread's 2 s-values

    float acc[4][2];                // [i][si]
    #pragma unroll
    for (int i = 0; i < 4; ++i) { acc[i][0] = 0.f; acc[i][1] = 0.f; }

    // encE flat float index: b*32768 + g*1024 + s*4 + j
    const float* __restrict__ ep = encE + ((size_t)b * 32 * SRC_LEN + s0) * 4;

    #pragma unroll 4
    for (int g = 0; g < 32; ++g) {
        const float* epg = ep + (size_t)g * SRC_LEN * 4;
        const float4 E0 = *(const float4*)(epg);         // s0   (16B)
        const float4 E1 = *(const float4*)(epg + 4);     // s0+1 (adjacent)
        const float4 vv = *(const float4*)(vS + g * 4);  // broadcast
        float4 n0, n1;
        n0.x = vv.x * E0.x; n0.y = vv.y * E0.y; n0.z = vv.z * E0.z; n0.w = vv.w * E0.w;
        n1.x = vv.x * E1.x; n1.y = vv.y * E1.y; n1.z = vv.z * E1.z; n1.w = vv.w * E1.w;

        #pragma unroll
        for (int i = 0; i < 4; ++i) {
            const float4 d = *(const float4*)(&dS[w * 4 + i][g * 4]);  // broadcast
            {
                const float x0 = E0.x + d.x, x1 = E0.y + d.y;
                const float x2 = E0.z + d.z, x3 = E0.w + d.w;
                const float a01 = x0 * x1, a23 = x2 * x3;
                const float den = a01 * a23;
                const float m01 = fmaf(n0.x, x1, n0.y * x0);
                const float m23 = fmaf(n0.z, x3, n0.w * x2);
                const float num = fmaf(m01, a23, m23 * a01);
                acc[i][0] = fmaf(num, __builtin_amdgcn_rcpf(den), acc[i][0]);
            }
            {
                const float x0 = E1.x + d.x, x1 = E1.y + d.y;
                const float x2 = E1.z + d.z, x3 = E1.w + d.w;
                const float a01 = x0 * x1, a23 = x2 * x3;
                const float den = a01 * a23;
                const float m01 = fmaf(n1.x, x1, n1.y * x0);
                const float m23 = fmaf(n1.z, x3, n1.w * x2);
                const float num = fmaf(m01, a23, m23 * a01);
                acc[i][1] = fmaf(num, __builtin_amdgcn_rcpf(den), acc[i][1]);
            }
        }
    }

    const float sv = sumvS;
    #pragma unroll
    for (int i = 0; i < 4; ++i) {
        float2 o;
        o.x = sv - 2.0f * acc[i][0];
        o.y = sv - 2.0f * acc[i][1];
        *(float2*)(out + ((size_t)(t0 + w * 4 + i) * BATCH + b) * SRC_LEN + s0) = o;
    }
}

extern "C" void kernel_launch(void* const* d_in, const int* in_sizes, int n_in,
                              void* d_out, int out_size, void* d_ws, size_t ws_size,
                              hipStream_t stream) {
    const float* dec_out  = (const float*)d_in[0];
    const float* enc_outs = (const float*)d_in[1];
    const float* W_s      = (const float*)d_in[2];
    const float* W_t      = (const float*)d_in[3];
    const float* b_t      = (const float*)d_in[4];
    const float* v_a      = (const float*)d_in[5];
    float* out = (float*)d_out;

    float* encE = (float*)d_ws;                              // B*32*S*4 = 4 MB : exp(-2*enc_att), [b][a>>2][s][4]
    float* decD = encE + (size_t)BATCH * ATT * SRC_LEN;      // T*B*A    = 4 MB : exp(+2*dec_att), [t][b][a]

    proj_mfma<<<256, 512, 0, stream>>>(dec_out, enc_outs, W_s, W_t, b_t, encE, decD);

    score_kernel<<<dim3(32, BATCH), 256, 0, stream>>>(encE, decD, v_a, out);
}

// Round 6
// 114.407 us; speedup vs baseline: 1.1209x; 1.1102x over previous
//
#include <hip/hip_runtime.h>

#define SRC_LEN 256
#define TRG_LEN 256
#define BATCH   32
#define HID     512
#define ATT     128
#define CSCALE  2.885390081777927f   // 2*log2(e): exp2(CSCALE*x) == exp(2x)

typedef float  f32x4  __attribute__((ext_vector_type(4)));
typedef short  bf16x8 __attribute__((ext_vector_type(8)));

// manual RNE fp32->bf16 (inputs are finite normals; NaN path not needed)
__device__ inline unsigned short bfr(float x) {
    unsigned u = __builtin_bit_cast(unsigned, x);
    return (unsigned short)((u + 0x7fffu + ((u >> 16) & 1u)) >> 16);
}
__device__ inline unsigned pk2(float a, float b) {
    return (unsigned)bfr(a) | ((unsigned)bfr(b) << 16);
}

// ---------------------------------------------------------------------------
// MFMA projection v5 (R0 measured-good, ~25-31 us) — byte-identical except
// the enc epilogue now stores F = exp(+2*enc_att) (sign flip) for score's
// F-form rational: term = v/(1 + F*d). b is the FAST block-id digit, so
// encE[b]/decD[.][b] are written on XCD b%8 — score's new grid reads them
// on the same XCD (see score v11 comment).
// ---------------------------------------------------------------------------
__global__ __launch_bounds__(512) void proj_mfma(
    const float* __restrict__ dec_out, const float* __restrict__ enc_outs,
    const float* __restrict__ W_s, const float* __restrict__ W_t,
    const float* __restrict__ b_t,
    float* __restrict__ encE, float* __restrict__ decD)
{
    __shared__ __align__(16) char smem[49152];
    char* aLb = smem;            // [2][64 rows][128 B] = 16 KB
    char* bLb = smem + 16384;    // [2][128 rows][128 B] = 32 KB

    const int tid   = threadIdx.x;
    const int blk   = blockIdx.x;
    const bool isDec = blk >= 128;
    const int bb    = blk & 31;
    const int r0    = ((isDec ? blk - 128 : blk) >> 5) * 64;  // s0 or t0
    const float* __restrict__ in = isDec ? dec_out : enc_outs;
    const float* __restrict__ W  = isDec ? W_t : W_s;

    const int lane   = tid & 63;
    const int w      = tid >> 6;        // 0..7
    const int woff_m = (w & 3) * 16;
    const int woff_n = (w >> 2) * 64;
    const int q      = lane >> 4;
    const int l15    = lane & 15;
    const int l7     = lane & 7;

    const int srow = tid >> 4;
    const int skc  = tid & 15;
    const int sg   = skc >> 1, shalf = skc & 1;
    const float* aGp = in + ((size_t)(r0 + srow) * BATCH + bb) * HID + skc * 4;
    const float* wGp = W + (size_t)srow * HID + skc * 4;

    float4 aR[2];   // A rows srow, srow+32
    float4 wR[4];   // W rows srow + it*32

    f32x4 acc[4];
    #pragma unroll
    for (int ni = 0; ni < 4; ++ni) acc[ni] = (f32x4)0.0f;

    #define LOADG(c)                                                          \
        {                                                                     \
            _Pragma("unroll")                                                 \
            for (int it = 0; it < 2; ++it)                                    \
                aR[it] = *(const float4*)(aGp + (size_t)it * 32 * BATCH * HID \
                                          + (c) * 64);                        \
            _Pragma("unroll")                                                 \
            for (int it = 0; it < 4; ++it)                                    \
                wR[it] = *(const float4*)(wGp + (size_t)it * 32 * HID         \
                                          + (c) * 64);                        \
        }

    #define STORES(buf)                                                      \
        {                                                                    \
            char* ab = aLb + (buf) * 8192;                                   \
            _Pragma("unroll")                                                \
            for (int it = 0; it < 2; ++it) {                                 \
                const int i = srow + it * 32;                                \
                uint2 u;                                                     \
                u.x = pk2(aR[it].x, aR[it].y);                               \
                u.y = pk2(aR[it].z, aR[it].w);                               \
                *(uint2*)(ab + i * 128 + ((sg ^ (i & 7)) << 4)               \
                          + shalf * 8) = u;                                  \
            }                                                                \
            char* bp = bLb + (buf) * 16384;                                  \
            _Pragma("unroll")                                                \
            for (int it = 0; it < 4; ++it) {                                 \
                const int rw = srow + it * 32;                               \
                uint2 u;                                                     \
                u.x = pk2(wR[it].x, wR[it].y);                               \
                u.y = pk2(wR[it].z, wR[it].w);                               \
                *(uint2*)(bp + rw * 128 + ((sg ^ (rw & 7)) << 4)             \
                          + shalf * 8) = u;                                  \
            }                                                                \
        }

    LOADG(0);
    STORES(0);
    __syncthreads();

    for (int c = 0; c < 8; ++c) {
        if (c < 7) LOADG(c + 1);
        const char* ab = aLb + (c & 1) * 8192;
        const char* bp = bLb + (c & 1) * 16384;
        #pragma unroll
        for (int s = 0; s < 2; ++s) {
            const int sw = ((s * 4 + q) ^ l7) * 16;
            bf16x8 af = *(const bf16x8*)(ab + (woff_m + l15) * 128 + sw);
            bf16x8 bfv[4];
            #pragma unroll
            for (int ni = 0; ni < 4; ++ni)
                bfv[ni] = *(const bf16x8*)(bp + (woff_n + ni * 16 + l15) * 128 + sw);
            #pragma unroll
            for (int ni = 0; ni < 4; ++ni)
                acc[ni] = __builtin_amdgcn_mfma_f32_16x16x32_bf16(
                    af, bfv[ni], acc[ni], 0, 0, 0);
        }
        if (c < 7) STORES((c + 1) & 1);
        __syncthreads();
    }

    if (!isDec) {
        // F = exp(+2*enc_att) -> LDS transpose (stride 132, float4-aligned)
        // -> [b][a>>2][s][4] store: one coalesced float4 per lane for score.
        float* T = (float*)smem;
        #pragma unroll
        for (int ni = 0; ni < 4; ++ni)
            #pragma unroll
            for (int r = 0; r < 4; ++r) {
                const int ml = woff_m + q * 4 + r;
                const int nl = woff_n + ni * 16 + l15;
                T[ml * 132 + nl] = __builtin_amdgcn_exp2f(CSCALE * acc[ni][r]);
            }
        __syncthreads();
        {
            const int m  = tid & 63;     // s-local
            const int g0 = tid >> 6;     // 0..7
            #pragma unroll
            for (int p = 0; p < 4; ++p) {
                const int gq = g0 + p * 8;          // a-quad 0..31
                float4 v = *(const float4*)(T + m * 132 + gq * 4);
                *(float4*)(encE + (((size_t)bb * 32 + gq) * SRC_LEN + r0 + m) * 4) = v;
            }
        }
    } else {
        // D = exp(+2*(dec_att + b_t)), natural [t][b][a] store
        float bt[4];
        #pragma unroll
        for (int ni = 0; ni < 4; ++ni) bt[ni] = b_t[woff_n + ni * 16 + l15];
        #pragma unroll
        for (int ni = 0; ni < 4; ++ni)
            #pragma unroll
            for (int r = 0; r < 4; ++r) {
                const int ml = woff_m + q * 4 + r;
                const int nl = woff_n + ni * 16 + l15;
                decD[((size_t)(r0 + ml) * BATCH + bb) * ATT + nl] =
                    __builtin_amdgcn_exp2f(CSCALE * (acc[ni][r] + bt[ni]));
            }
    }
    #undef LOADG
    #undef STORES
}

// ---------------------------------------------------------------------------
// Score v11 = v6 (best measured, ~36.5 us) + exactly two changes:
// 1) XCD write->read locality: grid is now (b=32, t_blk=64) with b FAST, so
//    linear_block%8 = b%8 — the same XCD class proj used to WRITE encE[b]
//    and decD[.][b] (proj is b-fast too). v6's t-fast grid scattered each b
//    across all 8 non-coherent L2s (4 MB working set/XCD = L2 thrash via
//    LLC); now each XCD touches only 4 b-slices (~1 MB), L2-hot from the
//    producer's own writes.
// 2) F-form rational: encE holds F=exp(+2enc); term = v/(1+F*d). The 4
//    shared n=v*E muls per g disappear (num uses v directly); x=E+d becomes
//    y=fma(F,d,1) (same count). 64->60 VALU/g, den>=1 (better conditioned).
// Everything else byte-identical to v6.
// ---------------------------------------------------------------------------
__global__ __launch_bounds__(256) void score_kernel(
    const float* __restrict__ encE, const float* __restrict__ decD,
    const float* __restrict__ v_a, float* __restrict__ out)
{
    __shared__ float dS[4 * ATT];
    __shared__ float vS[ATT];
    __shared__ float sumvS;

    const int tid = threadIdx.x;
    const int b   = blockIdx.x;          // FAST dim -> XCD = b%8 (matches proj)
    const int t0  = blockIdx.y * 4;

    if (tid < 128) {
        const int tt = tid >> 5, a4 = (tid & 31) * 4;
        *(float4*)(dS + tt * ATT + a4) =
            *(const float4*)(decD + ((size_t)(t0 + tt) * BATCH + b) * ATT + a4);
    } else if (tid < 160) {
        const int l = tid - 128;
        *(float4*)(vS + l * 4) = *(const float4*)(v_a + l * 4);
    }
    __syncthreads();
    if (tid < 64) {
        float x = vS[tid] + vS[tid + 64];
        #pragma unroll
        for (int o = 32; o > 0; o >>= 1) x += __shfl_down(x, o);
        if (tid == 0) sumvS = x;
    }
    __syncthreads();

    float acc0 = 0.f, acc1 = 0.f, acc2 = 0.f, acc3 = 0.f;
    const float* __restrict__ ep = encE + ((size_t)b * 32 * SRC_LEN + tid) * 4;

    #pragma unroll
    for (int g = 0; g < 32; ++g) {
        const float4 F  = *(const float4*)(ep + (size_t)g * SRC_LEN * 4);
        const float4 vv = *(const float4*)(vS + g * 4);

        #define TSTEP(ACC, DBASE)                                          \
        {                                                                  \
            const float4 d = *(const float4*)(DBASE + g * 4);              \
            const float y0 = fmaf(F.x, d.x, 1.0f);                         \
            const float y1 = fmaf(F.y, d.y, 1.0f);                         \
            const float y2 = fmaf(F.z, d.z, 1.0f);                         \
            const float y3 = fmaf(F.w, d.w, 1.0f);                         \
            const float a01 = y0 * y1, a23 = y2 * y3;                      \
            const float den = a01 * a23;                                   \
            const float m01 = fmaf(vv.x, y1, vv.y * y0);                   \
            const float m23 = fmaf(vv.z, y3, vv.w * y2);                   \
            const float num = fmaf(m01, a23, m23 * a01);                   \
            ACC = fmaf(num, __builtin_amdgcn_rcpf(den), ACC);              \
        }
        TSTEP(acc0, dS + 0 * ATT)
        TSTEP(acc1, dS + 1 * ATT)
        TSTEP(acc2, dS + 2 * ATT)
        TSTEP(acc3, dS + 3 * ATT)
        #undef TSTEP
    }

    const float sv = sumvS;
    out[((size_t)(t0 + 0) * BATCH + b) * SRC_LEN + tid] = sv - 2.0f * acc0;
    out[((size_t)(t0 + 1) * BATCH + b) * SRC_LEN + tid] = sv - 2.0f * acc1;
    out[((size_t)(t0 + 2) * BATCH + b) * SRC_LEN + tid] = sv - 2.0f * acc2;
    out[((size_t)(t0 + 3) * BATCH + b) * SRC_LEN + tid] = sv - 2.0f * acc3;
}

extern "C" void kernel_launch(void* const* d_in, const int* in_sizes, int n_in,
                              void* d_out, int out_size, void* d_ws, size_t ws_size,
                              hipStream_t stream) {
    const float* dec_out  = (const float*)d_in[0];
    const float* enc_outs = (const float*)d_in[1];
    const float* W_s      = (const float*)d_in[2];
    const float* W_t      = (const float*)d_in[3];
    const float* b_t      = (const float*)d_in[4];
    const float* v_a      = (const float*)d_in[5];
    float* out = (float*)d_out;

    float* encE = (float*)d_ws;                              // B*32*S*4 = 4 MB : exp(+2*enc_att), [b][a>>2][s][4]
    float* decD = encE + (size_t)BATCH * ATT * SRC_LEN;      // T*B*A    = 4 MB : exp(+2*dec_att), [t][b][a]

    proj_mfma<<<256, 512, 0, stream>>>(dec_out, enc_outs, W_s, W_t, b_t, encE, decD);

    // grid: b fast (XCD = b%8, matching proj's writes), t-blocks slow
    score_kernel<<<dim3(BATCH, TRG_LEN / 4), 256, 0, stream>>>(encE, decD, v_a, out);
}